// Round 9
// baseline (88.210 us; speedup 1.0000x reference)
//
#include <hip/hip_runtime.h>

// BPNet fused forward: E=16384, ORDER=3, D=13, RANK=128, NUM_PARAMS=4.
// R8: stage-1 deduplicated device-wide. Prep kernel computes ALL 16384
// T[node][ty][128] = relu(nodes@W1[ty]+b1) rows densely (f16-packed, in ws,
// L2-resident 4 MB), plus packs W2 to f16 and zeroes out. Fused kernel's
// stage 1 = 3 global uint4 loads/lane; LDS holds only W2 (40.7 KB), halving
// staging + LDS-pipe traffic. Facts via v_pk_mul_f16 on h2 pairs; stage 2
// dot2 + DPP row_sum16 reduction + 1 atomic per edge-slot.
// NUM_ITERS loop in reference is idempotent -> one iteration.

#define DD 13
#define OD 3
#define NP 4
#define RK 128

typedef unsigned int uint;
typedef _Float16 h2 __attribute__((ext_vector_type(2)));

// ws layout (dword offsets)
#define W2H_OFF 0                    // [12][13][64] h2: dword c -> ranks (2c,2c+1), dim dd
#define W2H_N   (12 * 13 * 64)       // 9984
#define HOB_OFF (W2H_OFF + W2H_N)    // [12][16] f32 (dd>=13 zeroed)
#define HOB_N   (12 * 16)            // 192
#define TAB_N   (HOB_OFF + HOB_N)    // 10176 dwords = 40704 B (LDS size)
#define T_OFF   16384                // [4096*4][64] h2: dword c -> ranks (2c,2c+1)
#define T_N     (16384 * 64)         // 1048576 dwords = 4 MB

// prep: aux work (zero + pack) item counts
#define ZERO_N4 13312                // 53248/4 uint4 stores
#define AUX_N   (ZERO_N4 + W2H_N + HOB_N)   // 23488
#define TBLK    4096                 // blocks doing T (4 pairs each)

__device__ __forceinline__ uint pk(float lo, float hi) {
    return __builtin_bit_cast(uint, __builtin_amdgcn_cvt_pkrtz(lo, hi));
}
__device__ __forceinline__ h2 ash2(uint w) { return __builtin_bit_cast(h2, w); }
__device__ __forceinline__ uint asu(h2 v) { return __builtin_bit_cast(uint, v); }

template <int CTRL>
__device__ __forceinline__ float dpp_add(float x) {
    int p = __builtin_amdgcn_update_dpp(0, __float_as_int(x), CTRL, 0xF, 0xF, false);
    return x + __int_as_float(p);
}
__device__ __forceinline__ float row_sum16(float x) {
    x = dpp_add<0xB1>(x);   // quad_perm xor1
    x = dpp_add<0x4E>(x);   // quad_perm xor2
    x = dpp_add<0x141>(x);  // row_half_mirror
    x = dpp_add<0x140>(x);  // row_mirror -> lane has its row-of-16 sum
    return x;
}

__global__ __launch_bounds__(256) void bpnet_prep(
    const float* __restrict__ nodes,      // [N, 13]
    const float* __restrict__ bp_params,  // [4,13,128]
    const float* __restrict__ bp_bias,    // [4,1,128]
    const float* __restrict__ ho_params,  // [3,4,128,13]
    const float* __restrict__ ho_bias,    // [3,4,1,13]
    uint* __restrict__ ws,
    uint* __restrict__ outz)              // zero 53248 dwords
{
    const int thr = threadIdx.x;
    if (blockIdx.x < TBLK) {
        // ---- T: one wave per (node,ty) pair; lane c -> ranks (2c,2c+1) ----
        const int c    = thr & 63;
        const int pair = blockIdx.x * 4 + (thr >> 6);
        const int ty   = pair & 3, node = pair >> 2;
        const float* nr = nodes + (size_t)node * DD;   // wave-uniform -> s_load
        float nv[DD];
#pragma unroll
        for (int d = 0; d < DD; ++d) nv[d] = nr[d];
        const float* wp = bp_params + (ty * DD) * RK + 2 * c;
        float lo = bp_bias[ty * RK + 2 * c];
        float hi = bp_bias[ty * RK + 2 * c + 1];
#pragma unroll
        for (int d = 0; d < DD; ++d) {
            const float2 w = *(const float2*)(wp + d * RK);  // coalesced dwordx2
            lo = fmaf(nv[d], w.x, lo);
            hi = fmaf(nv[d], w.y, hi);
        }
        ws[T_OFF + pair * 64 + c] = pk(fmaxf(lo, 0.f), fmaxf(hi, 0.f));
    } else {
        // ---- aux: zero out, pack W2H + HOB ----
        const int j = (blockIdx.x - TBLK) * 256 + thr;
        if (j < ZERO_N4) {
            ((uint4*)outz)[j] = uint4{0, 0, 0, 0};
        } else if (j < ZERO_N4 + W2H_N) {
            const int idx = j - ZERO_N4;
            const int c = idx & 63, q = idx >> 6;
            const int dd = q % 13, it = q / 13;
            ws[W2H_OFF + idx] = pk(ho_params[(size_t)(it * RK + 2 * c) * DD + dd],
                                   ho_params[(size_t)(it * RK + 2 * c + 1) * DD + dd]);
        } else if (j < AUX_N) {
            const int jj = j - (ZERO_N4 + W2H_N);
            const int dd = jj & 15, it = jj >> 4;
            ((float*)ws)[HOB_OFF + jj] = (dd < DD) ? ho_bias[it * DD + dd] : 0.f;
        }
    }
}

__global__ __launch_bounds__(512, 4) void bpnet_fused(
    const int*   __restrict__ edges,      // [E, 3]
    const int*   __restrict__ edge_types, // [E, 3]
    const uint*  __restrict__ ws,         // W2H/HOB tables + T
    float*       __restrict__ out)        // [N, 13] (pre-zeroed)
{
    __shared__ __align__(16) uint sh[TAB_N];
    const int tid  = threadIdx.x;
    const int lane = tid & 63;
    const int wv   = tid >> 6;        // 0..7
    const int e4   = lane >> 4;       // edge within wave's 4
    const int g    = lane & 15;       // rank octet 8g..8g+7
    const int eb   = (blockIdx.x * 8 + wv) * 4;

    // ---- wave metadata first (longest dependent chain: meta -> T loads) ----
    int ev = 0, tv = 0;
    if (lane < 12) {
        ev = edges[eb * OD + lane];
        tv = edge_types[eb * OD + lane];
    }
    int tg[OD], et[OD];
#pragma unroll
    for (int i = 0; i < OD; ++i) {
        tg[i] = __shfl(ev, e4 * OD + i, 64);
        et[i] = __shfl(tv, e4 * OD + i, 64);
    }

    // ---- stage 1 (precomputed): T rows, ranks 8g..8g+7 as 4 h2 dwords ----
    uint4 th[OD];
#pragma unroll
    for (int o = 0; o < OD; ++o)
        th[o] = *(const uint4*)(ws + T_OFF + (tg[o] * NP + et[o]) * 64 + 4 * g);

    // ---- stage W2 tables into LDS (overlaps the T loads above) ----
    for (int k4 = tid; k4 < TAB_N / 4; k4 += 512)
        ((uint4*)sh)[k4] = ((const uint4*)ws)[k4];
    __syncthreads();

    // ---- stage 2: facts via pk_mul_f16, dot2 vs W2H rows ----
#pragma unroll
    for (int i = 0; i < OD; ++i) {
        const int j = (i + 1) % OD, k = (i + 2) % OD;
        uint fh[4];
        fh[0] = asu(ash2(th[j].x) * ash2(th[k].x));   // v_pk_mul_f16
        fh[1] = asu(ash2(th[j].y) * ash2(th[k].y));
        fh[2] = asu(ash2(th[j].z) * ash2(th[k].z));
        fh[3] = asu(ash2(th[j].w) * ash2(th[k].w));
        const int it = i * NP + et[i];
        const uint* wb2 = sh + W2H_OFF + (it * DD) * 64 + 4 * g;
        float c[DD];
#pragma unroll
        for (int dd = 0; dd < DD; ++dd) {
            const uint4 w = *(const uint4*)(wb2 + dd * 64);
            float a = __builtin_amdgcn_fdot2(ash2(fh[0]), ash2(w.x), 0.f, false);
            a = __builtin_amdgcn_fdot2(ash2(fh[1]), ash2(w.y), a, false);
            a = __builtin_amdgcn_fdot2(ash2(fh[2]), ash2(w.z), a, false);
            a = __builtin_amdgcn_fdot2(ash2(fh[3]), ash2(w.w), a, false);
            c[dd] = a;
        }
#pragma unroll
        for (int dd = 0; dd < DD; ++dd) c[dd] = row_sum16(c[dd]);
        float q = c[0];
#pragma unroll
        for (int dd = 1; dd < DD; ++dd) q = (g == dd) ? c[dd] : q;
        q += ((const float*)(sh + HOB_OFF))[it * 16 + g];
        if (g < DD) atomicAdd(out + (size_t)tg[i] * DD + g, q);
    }
}

extern "C" void kernel_launch(void* const* d_in, const int* in_sizes, int n_in,
                              void* d_out, int out_size, void* d_ws, size_t ws_size,
                              hipStream_t stream) {
    const float* nodes      = (const float*)d_in[0];
    const float* bp_params  = (const float*)d_in[1];
    const float* bp_bias    = (const float*)d_in[2];
    const float* ho_params  = (const float*)d_in[3];
    const float* ho_bias    = (const float*)d_in[4];
    const int*   edges      = (const int*)d_in[5];
    const int*   edge_types = (const int*)d_in[6];
    float* out = (float*)d_out;
    uint*  ws  = (uint*)d_ws;

    const int E = in_sizes[5] / OD;   // 16384

    // prep: T table (4096 blocks x 4 pairs) + zero-out + pack (92 blocks)
    const int aux_blocks = (AUX_N + 255) / 256;
    bpnet_prep<<<TBLK + aux_blocks, 256, 0, stream>>>(
        nodes, bp_params, bp_bias, ho_params, ho_bias, ws, (uint*)out);

    // E/32 = 512 blocks x 8 waves x 4 edges = 16384
    bpnet_fused<<<E / 32, 512, 0, stream>>>(edges, edge_types, ws, out);
}